// Round 5
// baseline (391.492 us; speedup 1.0000x reference)
//
#include <hip/hip_runtime.h>
#include <math.h>

#define BS_TOK 16384   // B*S
#define DIM    2048    // D
#define NEXP   64      // E
#define DHID   1024    // D/2
#define GKS    4       // gate k-split
#define KSL    (DIM / GKS)

typedef __attribute__((ext_vector_type(8))) _Float16 f16x8;
typedef __attribute__((ext_vector_type(4))) float    f32x4;

#define GLOBAL_AS const __attribute__((address_space(1))) void*
#define LDS_AS    __attribute__((address_space(3))) void*

__device__ __forceinline__ float gelu_f(float x) {
  return 0.5f * x * (1.0f + erff(x * 0.70710678118654752440f));
}

// ---------------- fused: LayerNorm -> f16 H  +  W1 fp32 -> f16 ----------------
__global__ __launch_bounds__(256) void lnw1_kernel(const float* __restrict__ X,
                                                   const float* __restrict__ gamma,
                                                   const float* __restrict__ beta,
                                                   _Float16* __restrict__ H,
                                                   const float* __restrict__ W1,
                                                   _Float16* __restrict__ W1h) {
  const int tid = threadIdx.x;
  if (blockIdx.x >= BS_TOK / 4) {           // ---- w1cast part ----
    const int i = ((blockIdx.x - BS_TOK / 4) * 256 + tid) * 8;
    const float4 a = *(const float4*)(W1 + i);
    const float4 b = *(const float4*)(W1 + i + 4);
    f16x8 o;
    o[0] = (_Float16)a.x; o[1] = (_Float16)a.y; o[2] = (_Float16)a.z; o[3] = (_Float16)a.w;
    o[4] = (_Float16)b.x; o[5] = (_Float16)b.y; o[6] = (_Float16)b.z; o[7] = (_Float16)b.w;
    *(f16x8*)(W1h + i) = o;
    return;
  }
  // ---- ln part: one wave per token ----
  const int w    = tid >> 6, lane = tid & 63;
  const int t    = blockIdx.x * 4 + w;
  const float* xr = X + (size_t)t * DIM;
  float4 xv[8];
#pragma unroll
  for (int j = 0; j < 4; ++j) {
    const int c0 = (j * 64 + lane) * 8;
    xv[j * 2]     = *(const float4*)(xr + c0);
    xv[j * 2 + 1] = *(const float4*)(xr + c0 + 4);
  }
  float s = 0.f, q = 0.f;
#pragma unroll
  for (int j = 0; j < 8; ++j) {
    s += (xv[j].x + xv[j].y) + (xv[j].z + xv[j].w);
    q += (xv[j].x * xv[j].x + xv[j].y * xv[j].y) + (xv[j].z * xv[j].z + xv[j].w * xv[j].w);
  }
#pragma unroll
  for (int off = 32; off > 0; off >>= 1) {
    s += __shfl_xor(s, off);
    q += __shfl_xor(q, off);
  }
  const float mu  = s * (1.0f / DIM);
  const float var = q * (1.0f / DIM) - mu * mu;
  const float rs  = rsqrtf(var + 1e-5f);
#pragma unroll
  for (int j = 0; j < 4; ++j) {
    const int c0 = (j * 64 + lane) * 8;
    const float4 g0 = *(const float4*)(gamma + c0);
    const float4 g1 = *(const float4*)(gamma + c0 + 4);
    const float4 b0 = *(const float4*)(beta + c0);
    const float4 b1 = *(const float4*)(beta + c0 + 4);
    const float4 a = xv[j * 2], b = xv[j * 2 + 1];
    f16x8 h;
    h[0] = (_Float16)((a.x - mu) * rs * g0.x + b0.x);
    h[1] = (_Float16)((a.y - mu) * rs * g0.y + b0.y);
    h[2] = (_Float16)((a.z - mu) * rs * g0.z + b0.z);
    h[3] = (_Float16)((a.w - mu) * rs * g0.w + b0.w);
    h[4] = (_Float16)((b.x - mu) * rs * g1.x + b1.x);
    h[5] = (_Float16)((b.y - mu) * rs * g1.y + b1.y);
    h[6] = (_Float16)((b.z - mu) * rs * g1.z + b1.z);
    h[7] = (_Float16)((b.w - mu) * rs * g1.w + b1.w);
    *(f16x8*)(H + (size_t)t * DIM + c0) = h;
  }
}

// -------- gate partials: logitsP[ks] = X[:, ks] . Wg[:, ks]^T ----------
// 256x64 tile, 8x8 micro, 256 threads (4 waves).
#define GT_M 256
#define PX   260
#define PW   68
__global__ __launch_bounds__(256) void gate_kernel(const float* __restrict__ X,
                                                   const float* __restrict__ Wg,
                                                   float* __restrict__ logitsP) {
  __shared__ float sX[16][PX];   // [k][m]
  __shared__ float sW[16][PW];   // [k][e]
  const int tid  = threadIdx.x;
  const int m0   = blockIdx.x * GT_M;
  const int k0   = blockIdx.y * KSL;
  const int srow = tid >> 2;      // 0..63 staging row base
  const int skq  = tid & 3;       // k-quad
  const int ty   = tid >> 3;      // 0..31 token group (8 tokens each)
  const int tx   = tid & 7;       // 0..7  expert group (8 experts)
  const float* xb = X  + (size_t)(m0 + srow) * DIM + k0 + skq * 4;
  const float* wb = Wg + (size_t)srow * DIM + k0 + skq * 4;
  float acc[8][8] = {};
  float4 rx[4], rw;
#pragma unroll
  for (int g = 0; g < 4; ++g) rx[g] = *(const float4*)(xb + (size_t)(g * 64) * DIM);
  rw = *(const float4*)wb;
  for (int kt = 0; kt < KSL; kt += 16) {
    __syncthreads();
#pragma unroll
    for (int g = 0; g < 4; ++g) {
      sX[skq * 4 + 0][srow + g * 64] = rx[g].x;
      sX[skq * 4 + 1][srow + g * 64] = rx[g].y;
      sX[skq * 4 + 2][srow + g * 64] = rx[g].z;
      sX[skq * 4 + 3][srow + g * 64] = rx[g].w;
    }
    sW[skq * 4 + 0][srow] = rw.x;
    sW[skq * 4 + 1][srow] = rw.y;
    sW[skq * 4 + 2][srow] = rw.z;
    sW[skq * 4 + 3][srow] = rw.w;
    const int ktn = (kt + 16 < KSL) ? kt + 16 : 0;   // harmless reload on last iter
#pragma unroll
    for (int g = 0; g < 4; ++g) rx[g] = *(const float4*)(xb + (size_t)(g * 64) * DIM + ktn);
    rw = *(const float4*)(wb + ktn);
    __syncthreads();
#pragma unroll
    for (int k = 0; k < 16; ++k) {
      const float4 a0 = *(const float4*)&sX[k][ty * 8];
      const float4 a1 = *(const float4*)&sX[k][ty * 8 + 4];
      const float4 b0 = *(const float4*)&sW[k][tx * 8];
      const float4 b1 = *(const float4*)&sW[k][tx * 8 + 4];
      const float av[8] = {a0.x, a0.y, a0.z, a0.w, a1.x, a1.y, a1.z, a1.w};
      const float bv[8] = {b0.x, b0.y, b0.z, b0.w, b1.x, b1.y, b1.z, b1.w};
#pragma unroll
      for (int i = 0; i < 8; ++i)
#pragma unroll
        for (int j = 0; j < 8; ++j) acc[i][j] += av[i] * bv[j];
    }
  }
  float* op = logitsP + (size_t)blockIdx.y * ((size_t)BS_TOK * NEXP)
            + (size_t)(m0 + ty * 8) * NEXP + tx * 8;
#pragma unroll
  for (int i = 0; i < 8; ++i) {
    float4 o0, o1;
    o0.x = acc[i][0]; o0.y = acc[i][1]; o0.z = acc[i][2]; o0.w = acc[i][3];
    o1.x = acc[i][4]; o1.y = acc[i][5]; o1.z = acc[i][6]; o1.w = acc[i][7];
    *(float4*)(op + (size_t)i * NEXP)     = o0;
    *(float4*)(op + (size_t)i * NEXP + 4) = o1;
  }
}

// ------- predictor GEMM: H1 = gelu(H . W1^T); z[t] += sum_n H1*W2 (fused) -------
// 256x256 tile, BK=32, 8 waves, 3 LDS buffers (96 KB), prefetch distance 2
// K-tiles with counted boundary wait vmcnt(4) (tile t+1's loads are ~2 tiles
// old when waited on -> ~zero stall). Per phase NO explicit lgkmcnt drain:
// compiler emits fine-grained lgkmcnt(N) so MFMA head overlaps read tail.
// The only drain is at the tile boundary (lgkmcnt(0)+sched_barrier pins MFMA
// and reads on the safe side of the barrier that releases buffer writers).
// T2 octet swizzle (slot=quad^(col&3), src octet=(tid&3)^((tid>>2)&3)),
// T5 setprio around MFMA clusters, XCD-affine grid.
#define G2BM 256
#define G2BN 256
#define G2BK 32
#define G2NT (DIM / G2BK)   // 64 K-tiles

__global__ __launch_bounds__(512, 2) void g2_kernel(const _Float16* __restrict__ H,
                                                    const _Float16* __restrict__ W1h,
                                                    const float* __restrict__ W2,
                                                    float* __restrict__ diffz) {
  __shared__ __align__(16) _Float16 sA[3][G2BM * G2BK];
  __shared__ __align__(16) _Float16 sB[3][G2BN * G2BK];
  const int bid = blockIdx.x;
  const int xcd = bid & 7;
  const int loc = bid >> 3;                       // 0..31
  const int m0  = (xcd * 8 + (loc >> 2)) * G2BM;  // same-m blocks share an XCD
  const int n0  = (loc & 3) * G2BN;
  const int tid  = threadIdx.x;
  const int lane = tid & 63;
  const int w    = tid >> 6;
  const int wr   = w >> 2, wc = w & 3;            // 2 x 4 wave grid
  const int col  = lane & 15, quad = lane >> 4;
  const int sq   = (quad ^ (col & 3)) * 8;        // read: swizzled octet slot
  const int srow4 = tid >> 2;                     // 0..127 staging row
  const int ksw   = (tid & 3) ^ (srow4 & 3);      // source octet for linear LDS slot
  const _Float16* gA = H   + (size_t)(m0 + srow4) * DIM + ksw * 8;
  const _Float16* gB = W1h + (size_t)(n0 + srow4) * DIM + ksw * 8;
  f32x4 acc[8][4] = {};
#define G2_STAGE(bf_, kt_) do {                                                                             \
    __builtin_amdgcn_global_load_lds((GLOBAL_AS)(gA + (kt_)), (LDS_AS)(sA[bf_] + tid * 8), 16, 0, 0);        \
    __builtin_amdgcn_global_load_lds((GLOBAL_AS)(gA + (size_t)128 * DIM + (kt_)), (LDS_AS)(sA[bf_] + 4096 + tid * 8), 16, 0, 0); \
    __builtin_amdgcn_global_load_lds((GLOBAL_AS)(gB + (kt_)), (LDS_AS)(sB[bf_] + tid * 8), 16, 0, 0);        \
    __builtin_amdgcn_global_load_lds((GLOBAL_AS)(gB + (size_t)128 * DIM + (kt_)), (LDS_AS)(sB[bf_] + 4096 + tid * 8), 16, 0, 0); \
  } while (0)
  // prologue: tiles 0,1 staged (8 loads in flight); wait for tile 0 only.
  G2_STAGE(0, 0);
  G2_STAGE(1, G2BK);
  asm volatile("s_waitcnt vmcnt(4)" ::: "memory");
  __builtin_amdgcn_s_barrier();
  int cur = 0;
  for (int t = 0; t < G2NT; ++t) {
    const _Float16* A = sA[cur];
    const _Float16* B = sB[cur];
    const int nb = (cur >= 1) ? cur - 1 : 2;      // (cur+2)%3
    if (t + 2 < G2NT) G2_STAGE(nb, (t + 2) * G2BK);
    f16x8 af[4], bfr[4];
    // ---- phase 0: B frags + A mi 0-3 ----
#pragma unroll
    for (int ni = 0; ni < 4; ++ni)
      bfr[ni] = *(const f16x8*)(B + (wc * 64 + ni * 16 + col) * G2BK + sq);
#pragma unroll
    for (int mi = 0; mi < 4; ++mi)
      af[mi] = *(const f16x8*)(A + (wr * 128 + mi * 16 + col) * G2BK + sq);
    __builtin_amdgcn_s_barrier();
    __builtin_amdgcn_s_setprio(1);
#pragma unroll
    for (int mi = 0; mi < 4; ++mi)
#pragma unroll
      for (int ni = 0; ni < 4; ++ni)
        acc[mi][ni] = __builtin_amdgcn_mfma_f32_16x16x32_f16(af[mi], bfr[ni], acc[mi][ni], 0, 0, 0);
    __builtin_amdgcn_s_setprio(0);
    __builtin_amdgcn_s_barrier();
    // ---- phase 1: A mi 4-7, bfr reused ----
#pragma unroll
    for (int mi = 0; mi < 4; ++mi)
      af[mi] = *(const f16x8*)(A + (wr * 128 + (mi + 4) * 16 + col) * G2BK + sq);
    __builtin_amdgcn_s_barrier();
    __builtin_amdgcn_s_setprio(1);
#pragma unroll
    for (int mi = 0; mi < 4; ++mi)
#pragma unroll
      for (int ni = 0; ni < 4; ++ni)
        acc[mi + 4][ni] = __builtin_amdgcn_mfma_f32_16x16x32_f16(af[mi], bfr[ni], acc[mi + 4][ni], 0, 0, 0);
    __builtin_amdgcn_s_setprio(0);
    // ---- boundary: counted vmcnt (tile t+1 landed; t+2's 4 stay in flight);
    // lgkmcnt(0) is free here (reads already consumed); sched_barrier pins.
    if (t + 2 < G2NT) asm volatile("s_waitcnt vmcnt(4) lgkmcnt(0)" ::: "memory");
    else              asm volatile("s_waitcnt vmcnt(0) lgkmcnt(0)" ::: "memory");
    __builtin_amdgcn_sched_barrier(0);
    __builtin_amdgcn_s_barrier();
    cur = (cur == 2) ? 0 : cur + 1;
  }
#undef G2_STAGE
  // epilogue: gelu -> * W2 -> reduce over the 256 n-cols this block owns
  float w2v[4];
#pragma unroll
  for (int ni = 0; ni < 4; ++ni) w2v[ni] = W2[n0 + wc * 64 + ni * 16 + col];
#pragma unroll
  for (int mi = 0; mi < 8; ++mi) {
#pragma unroll
    for (int reg = 0; reg < 4; ++reg) {
      float v = 0.f;
#pragma unroll
      for (int ni = 0; ni < 4; ++ni) v += gelu_f(acc[mi][ni][reg]) * w2v[ni];
      v += __shfl_xor(v, 1);
      v += __shfl_xor(v, 2);
      v += __shfl_xor(v, 4);
      v += __shfl_xor(v, 8);
      if (col == 0)
        atomicAdd(diffz + m0 + wr * 128 + mi * 16 + quad * 4 + reg, v);
    }
  }
}

// ------ per-token finalize (+ folded importance/load scale via ticket) ------
__global__ __launch_bounds__(256) void finalize_kernel(const float* __restrict__ logitsP,
                                                       const float* __restrict__ diffz,
                                                       float* __restrict__ out_idx,
                                                       float* __restrict__ out_scores,
                                                       float* __restrict__ out_probs,
                                                       float* __restrict__ accs,
                                                       float* __restrict__ out_imp,
                                                       float* __restrict__ out_load) {
  const int tid  = threadIdx.x;
  const int w    = tid >> 6, lane = tid & 63;
  const size_t PS = (size_t)BS_TOK * NEXP;
  float acc_imp = 0.f, acc_load = 0.f;
  for (int it = 0; it < 8; ++it) {
    const int t    = blockIdx.x * 32 + it * 4 + w;
    const float* lp = logitsP + (size_t)t * NEXP + lane;
    const float L  = ((lp[0] + lp[PS]) + lp[2 * PS]) + lp[3 * PS];
    const float z  = diffz[t];
    const float d  = 1.0f / (1.0f + expf(-z));
    const float l  = L / (1.0f + d);          // TEMP == 1
    // softmax
    float m = l;
#pragma unroll
    for (int off = 32; off > 0; off >>= 1) m = fmaxf(m, __shfl_xor(m, off));
    float p = expf(l - m);
    float s = p;
#pragma unroll
    for (int off = 32; off > 0; off >>= 1) s += __shfl_xor(s, off);
    p /= s;
    // top-1 (jax tie-break: lower index wins)
    float v = l; int bi = lane;
#pragma unroll
    for (int off = 32; off > 0; off >>= 1) {
      const float ov = __shfl_xor(v, off);
      const int   oi = __shfl_xor(bi, off);
      if (ov > v || (ov == v && oi < bi)) { v = ov; bi = oi; }
    }
    const int i1 = bi;
    // top-2
    float v2 = (lane == i1) ? -INFINITY : l;
    int bi2 = lane;
#pragma unroll
    for (int off = 32; off > 0; off >>= 1) {
      const float ov = __shfl_xor(v2, off);
      const int   oi = __shfl_xor(bi2, off);
      if (ov > v2 || (ov == v2 && oi < bi2)) { v2 = ov; bi2 = oi; }
    }
    const int i2 = bi2;
    const float p1 = __shfl(p, i1);
    const float p2 = __shfl(p, i2);
    const float s1 = (1.0f - p1) + p1;        // straight-through, fp32-faithful
    const float s2 = (1.0f - p2) + p2;
    const float den = fmaxf(s1 + s2, 1e-9f);
    if (lane == 0) {
      out_idx[t * 2]        = (float)i1;
      out_idx[t * 2 + 1]    = (float)i2;
      out_scores[t * 2]     = s1 / den;
      out_scores[t * 2 + 1] = s2 / den;
    }
    out_probs[(size_t)t * NEXP + lane] = p;
    acc_imp  += p;
    acc_load += (lane == i1 || lane == i2) ? 1.0f : 0.0f;
  }
  __shared__ float s_imp[256];
  __shared__ float s_hard[256];
  s_imp[tid]  = acc_imp;
  s_hard[tid] = acc_load;
  __syncthreads();
  if (tid < 64) {
    const float si = s_imp[tid] + s_imp[64 + tid] + s_imp[128 + tid] + s_imp[192 + tid];
    const float sl = s_hard[tid] + s_hard[64 + tid] + s_hard[128 + tid] + s_hard[192 + tid];
    atomicAdd(accs + tid, si);
    atomicAdd(accs + 64 + tid, sl);
    __threadfence();   // make this thread's atomics device-visible before ticket
  }
  __shared__ int lastf;
  __syncthreads();
  if (tid == 0) {
    unsigned* cnt = (unsigned*)(accs + 128);
    lastf = (atomicAdd(cnt, 1u) == (unsigned)(BS_TOK / 32) - 1u);
  }
  __syncthreads();
  if (lastf && tid < 128) {
    const float v = atomicAdd(accs + tid, 0.0f);   // coherent (device-scope) read
    const float inv = 1.0f / 16384.0f;
    if (tid < 64) out_imp[tid]       = v * inv;
    else          out_load[tid - 64] = v * inv;
  }
}

extern "C" void kernel_launch(void* const* d_in, const int* in_sizes, int n_in,
                              void* d_out, int out_size, void* d_ws, size_t ws_size,
                              hipStream_t stream) {
  (void)in_sizes; (void)n_in; (void)out_size; (void)ws_size;
  const float* X     = (const float*)d_in[0];
  const float* Wg    = (const float*)d_in[1];
  const float* gamma = (const float*)d_in[2];
  const float* beta  = (const float*)d_in[3];
  const float* W1    = (const float*)d_in[4];
  const float* W2    = (const float*)d_in[5];
  float* out = (float*)d_out;

  char* ws = (char*)d_ws;
  _Float16* H       = (_Float16*)(ws);                    // 64 MB
  _Float16* W1h     = (_Float16*)(ws + 67108864ull);      // 4 MB
  float*    logitsP = (float*)  (ws + 71303168ull);       // 16 MB (4 k-split partials)
  float*    diffz   = (float*)  (ws + 88080384ull);       // 64 KB
  float*    accs    = (float*)  (ws + 88145920ull);       // 516 B (imp[64], load[64], cnt)

  // out layout (all float32): idx[32768] | scores[32768] | probs[1048576] | imp[64] | load[64]
  float* out_idx    = out;
  float* out_scores = out + 32768;
  float* out_probs  = out + 65536;
  float* out_imp    = out + 1114112;
  float* out_load   = out + 1114176;

  hipMemsetAsync(diffz, 0, 66560ull, stream);   // diffz + accs + ticket counter
  // order: gate streams cold X; lnw1 re-reads X L3-warm; g2 reads H L3-warm.
  gate_kernel<<<dim3(BS_TOK / GT_M, GKS), 256, 0, stream>>>(X, Wg, logitsP);
  lnw1_kernel<<<BS_TOK / 4 + (DHID * DIM) / (256 * 8), 256, 0, stream>>>(X, gamma, beta, H, W1, W1h);
  g2_kernel<<<(DHID / G2BN) * (BS_TOK / G2BM), 512, 0, stream>>>(H, W1h, W2, diffz);
  finalize_kernel<<<BS_TOK / 32, 256, 0, stream>>>(logitsP, diffz, out_idx, out_scores,
                                                   out_probs, accs, out_imp, out_load);
}

// Round 6
// 375.696 us; speedup vs baseline: 1.0420x; 1.0420x over previous
//
#include <hip/hip_runtime.h>
#include <math.h>

#define BS_TOK 16384   // B*S
#define DIM    2048    // D
#define NEXP   64      // E
#define DHID   1024    // D/2
#define GKS    4       // gate k-split
#define KSL    (DIM / GKS)

typedef __attribute__((ext_vector_type(8))) _Float16 f16x8;
typedef __attribute__((ext_vector_type(4))) float    f32x4;

#define GLOBAL_AS const __attribute__((address_space(1))) void*
#define LDS_AS    __attribute__((address_space(3))) void*

__device__ __forceinline__ float gelu_f(float x) {
  return 0.5f * x * (1.0f + erff(x * 0.70710678118654752440f));
}

// ---------------- fused: LayerNorm -> f16 H  +  W1 fp32 -> f16 ----------------
__global__ __launch_bounds__(256) void lnw1_kernel(const float* __restrict__ X,
                                                   const float* __restrict__ gamma,
                                                   const float* __restrict__ beta,
                                                   _Float16* __restrict__ H,
                                                   const float* __restrict__ W1,
                                                   _Float16* __restrict__ W1h) {
  const int tid = threadIdx.x;
  if (blockIdx.x >= BS_TOK / 4) {           // ---- w1cast part ----
    const int i = ((blockIdx.x - BS_TOK / 4) * 256 + tid) * 8;
    const float4 a = *(const float4*)(W1 + i);
    const float4 b = *(const float4*)(W1 + i + 4);
    f16x8 o;
    o[0] = (_Float16)a.x; o[1] = (_Float16)a.y; o[2] = (_Float16)a.z; o[3] = (_Float16)a.w;
    o[4] = (_Float16)b.x; o[5] = (_Float16)b.y; o[6] = (_Float16)b.z; o[7] = (_Float16)b.w;
    *(f16x8*)(W1h + i) = o;
    return;
  }
  // ---- ln part: one wave per token ----
  const int w    = tid >> 6, lane = tid & 63;
  const int t    = blockIdx.x * 4 + w;
  const float* xr = X + (size_t)t * DIM;
  float4 xv[8];
#pragma unroll
  for (int j = 0; j < 4; ++j) {
    const int c0 = (j * 64 + lane) * 8;
    xv[j * 2]     = *(const float4*)(xr + c0);
    xv[j * 2 + 1] = *(const float4*)(xr + c0 + 4);
  }
  float s = 0.f, q = 0.f;
#pragma unroll
  for (int j = 0; j < 8; ++j) {
    s += (xv[j].x + xv[j].y) + (xv[j].z + xv[j].w);
    q += (xv[j].x * xv[j].x + xv[j].y * xv[j].y) + (xv[j].z * xv[j].z + xv[j].w * xv[j].w);
  }
#pragma unroll
  for (int off = 32; off > 0; off >>= 1) {
    s += __shfl_xor(s, off);
    q += __shfl_xor(q, off);
  }
  const float mu  = s * (1.0f / DIM);
  const float var = q * (1.0f / DIM) - mu * mu;
  const float rs  = rsqrtf(var + 1e-5f);
#pragma unroll
  for (int j = 0; j < 4; ++j) {
    const int c0 = (j * 64 + lane) * 8;
    const float4 g0 = *(const float4*)(gamma + c0);
    const float4 g1 = *(const float4*)(gamma + c0 + 4);
    const float4 b0 = *(const float4*)(beta + c0);
    const float4 b1 = *(const float4*)(beta + c0 + 4);
    const float4 a = xv[j * 2], b = xv[j * 2 + 1];
    f16x8 h;
    h[0] = (_Float16)((a.x - mu) * rs * g0.x + b0.x);
    h[1] = (_Float16)((a.y - mu) * rs * g0.y + b0.y);
    h[2] = (_Float16)((a.z - mu) * rs * g0.z + b0.z);
    h[3] = (_Float16)((a.w - mu) * rs * g0.w + b0.w);
    h[4] = (_Float16)((b.x - mu) * rs * g1.x + b1.x);
    h[5] = (_Float16)((b.y - mu) * rs * g1.y + b1.y);
    h[6] = (_Float16)((b.z - mu) * rs * g1.z + b1.z);
    h[7] = (_Float16)((b.w - mu) * rs * g1.w + b1.w);
    *(f16x8*)(H + (size_t)t * DIM + c0) = h;
  }
}

// -------- gate partials: logitsP[ks] = X[:, ks] . Wg[:, ks]^T ----------
// 256x64 tile, 8x8 micro, 256 threads (4 waves).
#define GT_M 256
#define PX   260
#define PW   68
__global__ __launch_bounds__(256) void gate_kernel(const float* __restrict__ X,
                                                   const float* __restrict__ Wg,
                                                   float* __restrict__ logitsP) {
  __shared__ float sX[16][PX];   // [k][m]
  __shared__ float sW[16][PW];   // [k][e]
  const int tid  = threadIdx.x;
  const int m0   = blockIdx.x * GT_M;
  const int k0   = blockIdx.y * KSL;
  const int srow = tid >> 2;      // 0..63 staging row base
  const int skq  = tid & 3;       // k-quad
  const int ty   = tid >> 3;      // 0..31 token group (8 tokens each)
  const int tx   = tid & 7;       // 0..7  expert group (8 experts)
  const float* xb = X  + (size_t)(m0 + srow) * DIM + k0 + skq * 4;
  const float* wb = Wg + (size_t)srow * DIM + k0 + skq * 4;
  float acc[8][8] = {};
  float4 rx[4], rw;
#pragma unroll
  for (int g = 0; g < 4; ++g) rx[g] = *(const float4*)(xb + (size_t)(g * 64) * DIM);
  rw = *(const float4*)wb;
  for (int kt = 0; kt < KSL; kt += 16) {
    __syncthreads();
#pragma unroll
    for (int g = 0; g < 4; ++g) {
      sX[skq * 4 + 0][srow + g * 64] = rx[g].x;
      sX[skq * 4 + 1][srow + g * 64] = rx[g].y;
      sX[skq * 4 + 2][srow + g * 64] = rx[g].z;
      sX[skq * 4 + 3][srow + g * 64] = rx[g].w;
    }
    sW[skq * 4 + 0][srow] = rw.x;
    sW[skq * 4 + 1][srow] = rw.y;
    sW[skq * 4 + 2][srow] = rw.z;
    sW[skq * 4 + 3][srow] = rw.w;
    const int ktn = (kt + 16 < KSL) ? kt + 16 : 0;   // harmless reload on last iter
#pragma unroll
    for (int g = 0; g < 4; ++g) rx[g] = *(const float4*)(xb + (size_t)(g * 64) * DIM + ktn);
    rw = *(const float4*)(wb + ktn);
    __syncthreads();
#pragma unroll
    for (int k = 0; k < 16; ++k) {
      const float4 a0 = *(const float4*)&sX[k][ty * 8];
      const float4 a1 = *(const float4*)&sX[k][ty * 8 + 4];
      const float4 b0 = *(const float4*)&sW[k][tx * 8];
      const float4 b1 = *(const float4*)&sW[k][tx * 8 + 4];
      const float av[8] = {a0.x, a0.y, a0.z, a0.w, a1.x, a1.y, a1.z, a1.w};
      const float bv[8] = {b0.x, b0.y, b0.z, b0.w, b1.x, b1.y, b1.z, b1.w};
#pragma unroll
      for (int i = 0; i < 8; ++i)
#pragma unroll
        for (int j = 0; j < 8; ++j) acc[i][j] += av[i] * bv[j];
    }
  }
  float* op = logitsP + (size_t)blockIdx.y * ((size_t)BS_TOK * NEXP)
            + (size_t)(m0 + ty * 8) * NEXP + tx * 8;
#pragma unroll
  for (int i = 0; i < 8; ++i) {
    float4 o0, o1;
    o0.x = acc[i][0]; o0.y = acc[i][1]; o0.z = acc[i][2]; o0.w = acc[i][3];
    o1.x = acc[i][4]; o1.y = acc[i][5]; o1.z = acc[i][6]; o1.w = acc[i][7];
    *(float4*)(op + (size_t)i * NEXP)     = o0;
    *(float4*)(op + (size_t)i * NEXP + 4) = o1;
  }
}

// ------- predictor GEMM: H1 = gelu(H . W1^T); z[t] += sum_n H1*W2 (fused) -------
// m97-regime: 128x128 tile, BK=32, 256 thr (2x2 waves, 64x64/wave), SINGLE
// 16 KB LDS buffer, plain 2-barrier loop, __launch_bounds__(256,4) -> 4
// blocks/CU (16 waves): cross-BLOCK overlap hides the vmcnt drain at the
// barrier and anti-phases one block's LDS-read window against another's MFMA
// window (m114). Conflict-free involutive swizzle: source octet
// (tid&3)^((tid>>3)&3) into linear LDS; read slot quad^((col>>1)&3) -> within
// each 16-lane quad-group exactly 2 lanes/16B slot (free). XCD-affine grid.
#define G2BM 128
#define G2BN 128
#define G2BK 32
#define G2NT (DIM / G2BK)   // 64 K-tiles

__global__ __launch_bounds__(256, 4) void g2_kernel(const _Float16* __restrict__ H,
                                                    const _Float16* __restrict__ W1h,
                                                    const float* __restrict__ W2,
                                                    float* __restrict__ diffz) {
  __shared__ __align__(16) _Float16 sA[G2BM * G2BK];   // 8 KB
  __shared__ __align__(16) _Float16 sB[G2BN * G2BK];   // 8 KB
  const int bid = blockIdx.x;
  const int xcd = bid & 7;
  const int loc = bid >> 3;                       // 0..127
  const int m0  = (xcd * 16 + (loc >> 3)) * G2BM; // same-m n-blocks share an XCD
  const int n0  = (loc & 7) * G2BN;
  const int tid  = threadIdx.x;
  const int lane = tid & 63;
  const int w    = tid >> 6;
  const int wr   = w >> 1, wc = w & 1;            // 2 x 2 wave grid
  const int col  = lane & 15, quad = lane >> 4;
  const int sq   = (quad ^ ((col >> 1) & 3)) * 8; // read slot (f16 elems)
  const int srow = tid >> 2;                      // 0..63 staging row
  const int ksw  = (tid & 3) ^ ((tid >> 3) & 3);  // pre-swizzled source octet
  const _Float16* gA = H   + (size_t)(m0 + srow) * DIM + ksw * 8;
  const _Float16* gB = W1h + (size_t)(n0 + srow) * DIM + ksw * 8;
  f32x4 acc[4][4] = {};
  for (int t = 0; t < G2NT; ++t) {
    const int kt = t * G2BK;
    __syncthreads();   // all waves done reading previous tile
    __builtin_amdgcn_global_load_lds((GLOBAL_AS)(gA + kt), (LDS_AS)(sA + tid * 8), 16, 0, 0);
    __builtin_amdgcn_global_load_lds((GLOBAL_AS)(gA + (size_t)64 * DIM + kt), (LDS_AS)(sA + 2048 + tid * 8), 16, 0, 0);
    __builtin_amdgcn_global_load_lds((GLOBAL_AS)(gB + kt), (LDS_AS)(sB + tid * 8), 16, 0, 0);
    __builtin_amdgcn_global_load_lds((GLOBAL_AS)(gB + (size_t)64 * DIM + kt), (LDS_AS)(sB + 2048 + tid * 8), 16, 0, 0);
    __syncthreads();   // implicit vmcnt(0) drain; covered by other blocks on CU
    f16x8 af[4], bf[4];
#pragma unroll
    for (int mi = 0; mi < 4; ++mi)
      af[mi] = *(const f16x8*)(sA + (wr * 64 + mi * 16 + col) * G2BK + sq);
#pragma unroll
    for (int ni = 0; ni < 4; ++ni)
      bf[ni] = *(const f16x8*)(sB + (wc * 64 + ni * 16 + col) * G2BK + sq);
    __builtin_amdgcn_s_setprio(1);
#pragma unroll
    for (int mi = 0; mi < 4; ++mi)
#pragma unroll
      for (int ni = 0; ni < 4; ++ni)
        acc[mi][ni] = __builtin_amdgcn_mfma_f32_16x16x32_f16(af[mi], bf[ni], acc[mi][ni], 0, 0, 0);
    __builtin_amdgcn_s_setprio(0);
  }
  // epilogue: gelu -> * W2 -> reduce over the 128 n-cols this block owns
  float w2v[4];
#pragma unroll
  for (int ni = 0; ni < 4; ++ni) w2v[ni] = W2[n0 + wc * 64 + ni * 16 + col];
#pragma unroll
  for (int mi = 0; mi < 4; ++mi) {
#pragma unroll
    for (int reg = 0; reg < 4; ++reg) {
      float v = 0.f;
#pragma unroll
      for (int ni = 0; ni < 4; ++ni) v += gelu_f(acc[mi][ni][reg]) * w2v[ni];
      v += __shfl_xor(v, 1);
      v += __shfl_xor(v, 2);
      v += __shfl_xor(v, 4);
      v += __shfl_xor(v, 8);
      if (col == 0)
        atomicAdd(diffz + m0 + wr * 64 + mi * 16 + quad * 4 + reg, v);
    }
  }
}

// ------ per-token finalize (+ folded importance/load scale via ticket) ------
__global__ __launch_bounds__(256) void finalize_kernel(const float* __restrict__ logitsP,
                                                       const float* __restrict__ diffz,
                                                       float* __restrict__ out_idx,
                                                       float* __restrict__ out_scores,
                                                       float* __restrict__ out_probs,
                                                       float* __restrict__ accs,
                                                       float* __restrict__ out_imp,
                                                       float* __restrict__ out_load) {
  const int tid  = threadIdx.x;
  const int w    = tid >> 6, lane = tid & 63;
  const size_t PS = (size_t)BS_TOK * NEXP;
  float acc_imp = 0.f, acc_load = 0.f;
  for (int it = 0; it < 8; ++it) {
    const int t    = blockIdx.x * 32 + it * 4 + w;
    const float* lp = logitsP + (size_t)t * NEXP + lane;
    const float L  = ((lp[0] + lp[PS]) + lp[2 * PS]) + lp[3 * PS];
    const float z  = diffz[t];
    const float d  = 1.0f / (1.0f + expf(-z));
    const float l  = L / (1.0f + d);          // TEMP == 1
    // softmax
    float m = l;
#pragma unroll
    for (int off = 32; off > 0; off >>= 1) m = fmaxf(m, __shfl_xor(m, off));
    float p = expf(l - m);
    float s = p;
#pragma unroll
    for (int off = 32; off > 0; off >>= 1) s += __shfl_xor(s, off);
    p /= s;
    // top-1 (jax tie-break: lower index wins)
    float v = l; int bi = lane;
#pragma unroll
    for (int off = 32; off > 0; off >>= 1) {
      const float ov = __shfl_xor(v, off);
      const int   oi = __shfl_xor(bi, off);
      if (ov > v || (ov == v && oi < bi)) { v = ov; bi = oi; }
    }
    const int i1 = bi;
    // top-2
    float v2 = (lane == i1) ? -INFINITY : l;
    int bi2 = lane;
#pragma unroll
    for (int off = 32; off > 0; off >>= 1) {
      const float ov = __shfl_xor(v2, off);
      const int   oi = __shfl_xor(bi2, off);
      if (ov > v2 || (ov == v2 && oi < bi2)) { v2 = ov; bi2 = oi; }
    }
    const int i2 = bi2;
    const float p1 = __shfl(p, i1);
    const float p2 = __shfl(p, i2);
    const float s1 = (1.0f - p1) + p1;        // straight-through, fp32-faithful
    const float s2 = (1.0f - p2) + p2;
    const float den = fmaxf(s1 + s2, 1e-9f);
    if (lane == 0) {
      out_idx[t * 2]        = (float)i1;
      out_idx[t * 2 + 1]    = (float)i2;
      out_scores[t * 2]     = s1 / den;
      out_scores[t * 2 + 1] = s2 / den;
    }
    out_probs[(size_t)t * NEXP + lane] = p;
    acc_imp  += p;
    acc_load += (lane == i1 || lane == i2) ? 1.0f : 0.0f;
  }
  __shared__ float s_imp[256];
  __shared__ float s_hard[256];
  s_imp[tid]  = acc_imp;
  s_hard[tid] = acc_load;
  __syncthreads();
  if (tid < 64) {
    const float si = s_imp[tid] + s_imp[64 + tid] + s_imp[128 + tid] + s_imp[192 + tid];
    const float sl = s_hard[tid] + s_hard[64 + tid] + s_hard[128 + tid] + s_hard[192 + tid];
    atomicAdd(accs + tid, si);
    atomicAdd(accs + 64 + tid, sl);
    __threadfence();   // make this thread's atomics device-visible before ticket
  }
  __shared__ int lastf;
  __syncthreads();
  if (tid == 0) {
    unsigned* cnt = (unsigned*)(accs + 128);
    lastf = (atomicAdd(cnt, 1u) == (unsigned)(BS_TOK / 32) - 1u);
  }
  __syncthreads();
  if (lastf && tid < 128) {
    const float v = atomicAdd(accs + tid, 0.0f);   // coherent (device-scope) read
    const float inv = 1.0f / 16384.0f;
    if (tid < 64) out_imp[tid]       = v * inv;
    else          out_load[tid - 64] = v * inv;
  }
}

extern "C" void kernel_launch(void* const* d_in, const int* in_sizes, int n_in,
                              void* d_out, int out_size, void* d_ws, size_t ws_size,
                              hipStream_t stream) {
  (void)in_sizes; (void)n_in; (void)out_size; (void)ws_size;
  const float* X     = (const float*)d_in[0];
  const float* Wg    = (const float*)d_in[1];
  const float* gamma = (const float*)d_in[2];
  const float* beta  = (const float*)d_in[3];
  const float* W1    = (const float*)d_in[4];
  const float* W2    = (const float*)d_in[5];
  float* out = (float*)d_out;

  char* ws = (char*)d_ws;
  _Float16* H       = (_Float16*)(ws);                    // 64 MB
  _Float16* W1h     = (_Float16*)(ws + 67108864ull);      // 4 MB
  float*    logitsP = (float*)  (ws + 71303168ull);       // 16 MB (4 k-split partials)
  float*    diffz   = (float*)  (ws + 88080384ull);       // 64 KB
  float*    accs    = (float*)  (ws + 88145920ull);       // 516 B (imp[64], load[64], cnt)

  // out layout (all float32): idx[32768] | scores[32768] | probs[1048576] | imp[64] | load[64]
  float* out_idx    = out;
  float* out_scores = out + 32768;
  float* out_probs  = out + 65536;
  float* out_imp    = out + 1114112;
  float* out_load   = out + 1114176;

  hipMemsetAsync(diffz, 0, 66560ull, stream);   // diffz + accs + ticket counter
  // order: gate streams cold X; lnw1 re-reads X L3-warm; g2 reads H L3-warm.
  gate_kernel<<<dim3(BS_TOK / GT_M, GKS), 256, 0, stream>>>(X, Wg, logitsP);
  lnw1_kernel<<<BS_TOK / 4 + (DHID * DIM) / (256 * 8), 256, 0, stream>>>(X, gamma, beta, H, W1, W1h);
  g2_kernel<<<(DHID / G2BN) * (BS_TOK / G2BM), 256, 0, stream>>>(H, W1h, W2, diffz);
  finalize_kernel<<<BS_TOK / 32, 256, 0, stream>>>(logitsP, diffz, out_idx, out_scores,
                                                   out_probs, accs, out_imp, out_load);
}